// Round 4
// baseline (308.303 us; speedup 1.0000x reference)
//
#include <hip/hip_runtime.h>

// MyLSTM: 2-layer LSTM (input=3, hidden=4) + MLP head (4->4 tanh -> 1), B=4096, T=1024.
//
// R4: single-wave software pipeline. One instruction stream per chain group carries TWO
// independent dependency chains per iteration: [layer1 + head](t-1) and layer0(t).
// L1 reads the h0 quad registers (still holding step t-1) before L0 overwrites them --
// pure register renaming, no LDS ring, no barriers, no stage imbalance (R3 lost ~27%
// to producer/consumer imbalance + chunk barriers: VALUBusy 73%).
//
// Lane layout per 16-lane chain group: unit u=(l>>2)&3, role rho=l&3 (0=i,1=f,2=g,3=o);
// gate row r = rho*4+u. All cross-lane traffic is DPP (quad_perm broadcasts for i/f/g/o;
// half_mirror/ror8/mirror replicate quad-uniform h across units -- valid because h is
// quad-uniform, so lane^7==lane^4 etc. on this data). x is prefetched 2 steps deep.
// 4096 chains * 16 lanes = 1024 waves = 1 wave/SIMD; stall hiding comes from the two
// interleaved chains (ILP), not TLP.

#define T_STEPS 1024
#define BATCH   4096

__device__ __forceinline__ float fast_exp2(float x) {
#if __has_builtin(__builtin_amdgcn_exp2f)
    return __builtin_amdgcn_exp2f(x);
#else
    return exp2f(x);
#endif
}

__device__ __forceinline__ float fast_rcp(float x) {
#if __has_builtin(__builtin_amdgcn_rcpf)
    return __builtin_amdgcn_rcpf(x);
#else
    return 1.0f / x;
#endif
}

// tanh(x) = 2*sigmoid(2x) - 1 = 2/(1+exp2(-2.885390x)) - 1
__device__ __forceinline__ float fast_tanh(float x) {
    return 2.0f * fast_rcp(1.0f + fast_exp2(-2.88539008f * x)) - 1.0f;
}

template <int CTRL>
__device__ __forceinline__ float dpp_mov(float v) {
    int i = __builtin_bit_cast(int, v);
    i = __builtin_amdgcn_mov_dpp(i, CTRL, 0xF, 0xF, true);
    return __builtin_bit_cast(float, i);
}

#define DPP_QUAD_BCAST0 0x00   // quad_perm [0,0,0,0] -> i gate
#define DPP_QUAD_BCAST1 0x55   // quad_perm [1,1,1,1] -> f gate
#define DPP_QUAD_BCAST2 0xAA   // quad_perm [2,2,2,2] -> g gate
#define DPP_QUAD_BCAST3 0xFF   // quad_perm [3,3,3,3] -> o gate
#define DPP_ROR8        0x128  // (l+8)&15 == l^8 -> u^2
#define DPP_MIRROR      0x140  // l^15 -> u^3 on quad-uniform data
#define DPP_HALF_MIRROR 0x141  // l^7  -> u^1 on quad-uniform data

__global__ __launch_bounds__(256) void lstm_merged_kernel(
    const float* __restrict__ x,
    const float* __restrict__ W_ih0, const float* __restrict__ W_hh0,
    const float* __restrict__ b_ih0, const float* __restrict__ b_hh0,
    const float* __restrict__ W_ih1, const float* __restrict__ W_hh1,
    const float* __restrict__ b_ih1, const float* __restrict__ b_hh1,
    const float* __restrict__ W1, const float* __restrict__ b1,
    const float* __restrict__ W2, const float* __restrict__ b2,
    float* __restrict__ out)
{
    const int tid  = threadIdx.x;
    const int idx  = tid & 15;          // lane within 16-lane chain group
    const int rho  = tid & 3;           // role: 0=i,1=f,2=g,3=o
    const int u    = (tid >> 2) & 3;    // hidden unit
    const int r    = rho * 4 + u;       // gate row in the 16-row weight matrices
    const int batch = blockIdx.x * 16 + (tid >> 4);

    // Per-lane activation constants: role g (rho==2) uses tanh = 2*sigma(2x)-1.
    const float am = (rho == 2) ? -2.88539008f : -1.44269504f;
    const float aa = (rho == 2) ? 2.0f : 1.0f;
    const float ab = (rho == 2) ? -1.0f : 0.0f;

    const float wx0 = W_ih0[r * 3 + 0];
    const float wx1 = W_ih0[r * 3 + 1];
    const float wx2 = W_ih0[r * 3 + 2];
    const float bias0 = b_ih0[r] + b_hh0[r];
    const float bias1 = b_ih1[r] + b_hh1[r];

    float wh0[4], wi1[4], wh1[4], w1p[4];
#pragma unroll
    for (int k = 0; k < 4; ++k) {
        wh0[k] = W_hh0[r * 4 + (u ^ k)];   // order: own, ^1, ^2, ^3
        wi1[k] = W_ih1[r * 4 + (u ^ k)];
        wh1[k] = W_hh1[r * 4 + (u ^ k)];
        w1p[k] = W1[u * 4 + (u ^ k)];
    }
    const float b1u = b1[u];
    const float w2u = W2[u];
    const float b2v = b2[0];

    float h0, c0, h0b, h0c, h0d;
    float h1 = 0.f, c1 = 0.f, h1b = 0.f, h1c = 0.f, h1d = 0.f;
    float ysave = 0.f;

    const float* xp = x + (size_t)batch * T_STEPS * 3;
    float* op = out + (size_t)batch * T_STEPS;

    // Prime the 2-deep x prefetch and peel L0 step 0 (h0,c0 start at zero).
    float ax0 = xp[0], ax1 = xp[1], ax2 = xp[2];
    float bx0 = xp[3], bx1 = xp[4], bx2 = xp[5];
    xp += 6;
    {
        float pre0 = bias0 + wx0 * ax0 + wx1 * ax1 + wx2 * ax2;
        float a0 = aa * fast_rcp(1.0f + fast_exp2(am * pre0)) + ab;
        float gi = dpp_mov<DPP_QUAD_BCAST0>(a0);
        float gg = dpp_mov<DPP_QUAD_BCAST2>(a0);
        float go = dpp_mov<DPP_QUAD_BCAST3>(a0);
        c0 = gi * gg;
        h0 = go * fast_tanh(c0);
        h0b = dpp_mov<DPP_HALF_MIRROR>(h0);
        h0c = dpp_mov<DPP_ROR8>(h0);
        h0d = dpp_mov<DPP_MIRROR>(h0);
    }
    // shift pipeline: ax = x(1), bx = x(2)
    ax0 = bx0; ax1 = bx1; ax2 = bx2;
    bx0 = xp[0]; bx1 = xp[1]; bx2 = xp[2];
    xp += 3;

#pragma unroll 4
    for (int t = 1; t < T_STEPS; ++t) {
        // ======== chain A: layer 1 + head for step t-1 (reads h0 quad of t-1) ========
        float pre1 = bias1
                   + wi1[0] * h0 + wi1[1] * h0b + wi1[2] * h0c + wi1[3] * h0d
                   + wh1[0] * h1 + wh1[1] * h1b + wh1[2] * h1c + wh1[3] * h1d;
        float a1 = aa * fast_rcp(1.0f + fast_exp2(am * pre1)) + ab;
        float gi1 = dpp_mov<DPP_QUAD_BCAST0>(a1);
        float gf1 = dpp_mov<DPP_QUAD_BCAST1>(a1);
        float gg1 = dpp_mov<DPP_QUAD_BCAST2>(a1);
        float go1 = dpp_mov<DPP_QUAD_BCAST3>(a1);
        c1 = gf1 * c1 + gi1 * gg1;
        h1 = go1 * fast_tanh(c1);
        h1b = dpp_mov<DPP_HALF_MIRROR>(h1);
        h1c = dpp_mov<DPP_ROR8>(h1);
        h1d = dpp_mov<DPP_MIRROR>(h1);

        float zp = b1u + w1p[0] * h1 + w1p[1] * h1b + w1p[2] * h1c + w1p[3] * h1d;
        float z  = fast_tanh(zp);
        float yv = w2u * z;                              // quad-uniform
        float t1 = yv + dpp_mov<DPP_ROR8>(yv);           // + unit u^2
        float y  = t1 + dpp_mov<DPP_MIRROR>(t1) + b2v;   // + units u^1,u^3

        const int tp = t - 1;
        ysave = ((tp & 15) == idx) ? y : ysave;

        // ======== chain B: layer 0 for step t (independent of chain A) ========
        const float x0 = ax0, x1 = ax1, x2 = ax2;
        ax0 = bx0; ax1 = bx1; ax2 = bx2;
        const float* xl = (t < T_STEPS - 2) ? xp : (xp - 6);  // clamped tail prefetch
        bx0 = xl[0]; bx1 = xl[1]; bx2 = xl[2];
        xp += 3;

        float pre0 = bias0 + wx0 * x0 + wx1 * x1 + wx2 * x2
                   + wh0[0] * h0 + wh0[1] * h0b + wh0[2] * h0c + wh0[3] * h0d;
        float a0 = aa * fast_rcp(1.0f + fast_exp2(am * pre0)) + ab;
        float gi = dpp_mov<DPP_QUAD_BCAST0>(a0);
        float gf = dpp_mov<DPP_QUAD_BCAST1>(a0);
        float gg = dpp_mov<DPP_QUAD_BCAST2>(a0);
        float go = dpp_mov<DPP_QUAD_BCAST3>(a0);
        c0 = gf * c0 + gi * gg;
        h0 = go * fast_tanh(c0);
        h0b = dpp_mov<DPP_HALF_MIRROR>(h0);
        h0c = dpp_mov<DPP_ROR8>(h0);
        h0d = dpp_mov<DPP_MIRROR>(h0);

        if ((tp & 15) == 15) {
            op[(tp & ~15) + idx] = ysave;   // 16 consecutive floats per chain: coalesced
        }
    }

    // Epilogue: layer 1 + head for step 1023, then final staged store.
    {
        float pre1 = bias1
                   + wi1[0] * h0 + wi1[1] * h0b + wi1[2] * h0c + wi1[3] * h0d
                   + wh1[0] * h1 + wh1[1] * h1b + wh1[2] * h1c + wh1[3] * h1d;
        float a1 = aa * fast_rcp(1.0f + fast_exp2(am * pre1)) + ab;
        float gi1 = dpp_mov<DPP_QUAD_BCAST0>(a1);
        float gf1 = dpp_mov<DPP_QUAD_BCAST1>(a1);
        float gg1 = dpp_mov<DPP_QUAD_BCAST2>(a1);
        float go1 = dpp_mov<DPP_QUAD_BCAST3>(a1);
        c1 = gf1 * c1 + gi1 * gg1;
        h1 = go1 * fast_tanh(c1);
        h1b = dpp_mov<DPP_HALF_MIRROR>(h1);
        h1c = dpp_mov<DPP_ROR8>(h1);
        h1d = dpp_mov<DPP_MIRROR>(h1);

        float zp = b1u + w1p[0] * h1 + w1p[1] * h1b + w1p[2] * h1c + w1p[3] * h1d;
        float z  = fast_tanh(zp);
        float yv = w2u * z;
        float t1 = yv + dpp_mov<DPP_ROR8>(yv);
        float y  = t1 + dpp_mov<DPP_MIRROR>(t1) + b2v;

        ysave = (15 == idx) ? y : ysave;            // tp = 1023, (1023 & 15) == 15
        op[(T_STEPS - 16) + idx] = ysave;
    }
}

extern "C" void kernel_launch(void* const* d_in, const int* in_sizes, int n_in,
                              void* d_out, int out_size, void* d_ws, size_t ws_size,
                              hipStream_t stream) {
    const float* x     = (const float*)d_in[0];
    const float* W_ih0 = (const float*)d_in[1];
    const float* W_hh0 = (const float*)d_in[2];
    const float* b_ih0 = (const float*)d_in[3];
    const float* b_hh0 = (const float*)d_in[4];
    const float* W_ih1 = (const float*)d_in[5];
    const float* W_hh1 = (const float*)d_in[6];
    const float* b_ih1 = (const float*)d_in[7];
    const float* b_hh1 = (const float*)d_in[8];
    const float* W1    = (const float*)d_in[9];
    const float* b1    = (const float*)d_in[10];
    const float* W2    = (const float*)d_in[11];
    const float* b2    = (const float*)d_in[12];
    float* out = (float*)d_out;

    dim3 grid(BATCH / 16);   // 256 blocks, 16 chains each
    dim3 block(256);         // 4 waves/block, 4 chains/wave; 1024 waves total
    lstm_merged_kernel<<<grid, block, 0, stream>>>(
        x, W_ih0, W_hh0, b_ih0, b_hh0, W_ih1, W_hh1, b_ih1, b_hh1,
        W1, b1, W2, b2, out);
}

// Round 5
// 278.972 us; speedup vs baseline: 1.1051x; 1.1051x over previous
//
#include <hip/hip_runtime.h>

// MyLSTM: 2-layer LSTM (input=3, hidden=4) + MLP head (4->4 tanh -> 1), B=4096, T=1024.
//
// R5: 3-stage wave pipeline. Each 16-lane group owns one chain; each group of 4 chains
// ("triple") is serviced by THREE waves:
//   stage 0: layer-0 LSTM          (~98 cyc/step issue)
//   stage 1: layer-1 LSTM          (~88)
//   stage 2: MLP head + store      (~50, mostly idle -> latency hiding for the others)
// h0 and h1 flow through slim double-buffered LDS rings holding plain h[4] per chain
// (rho==0 lanes ds_write_b32; consumers ds_read_b128 broadcast, plain-order weights).
// Pipeline depth 2 chunks of 16 steps; one __syncthreads per chunk iteration.
// Block = 768 threads = 12 waves = 4 triples: wave w -> SIMD w%4 puts one wave of each
// stage on every SIMD; 256 blocks = 1 block/CU, 12 waves/CU = 3 waves/SIMD.
// R4 lesson: TLP beats compiler-scheduled ILP here (R4 merged-ILP regressed to 61% VALUBusy);
// R3's 2-wave split stalled 27% on stage imbalance (98 vs 130 cyc) -- this evens it out.
//
// Lane layout per 16-lane group: unit u=(l>>2)&3, role rho=l&3 (0=i,1=f,2=g,3=o);
// gate row r = rho*4+u. Cross-lane traffic inside a stage is DPP only.

#define T_STEPS 1024
#define BATCH   4096
#define CHUNK   16
#define NCHUNK  (T_STEPS / CHUNK)

__device__ __forceinline__ float fast_exp2(float x) {
#if __has_builtin(__builtin_amdgcn_exp2f)
    return __builtin_amdgcn_exp2f(x);
#else
    return exp2f(x);
#endif
}

__device__ __forceinline__ float fast_rcp(float x) {
#if __has_builtin(__builtin_amdgcn_rcpf)
    return __builtin_amdgcn_rcpf(x);
#else
    return 1.0f / x;
#endif
}

// tanh(x) = 2*sigmoid(2x) - 1 = 2/(1+exp2(-2.885390x)) - 1
__device__ __forceinline__ float fast_tanh(float x) {
    return 2.0f * fast_rcp(1.0f + fast_exp2(-2.88539008f * x)) - 1.0f;
}

template <int CTRL>
__device__ __forceinline__ float dpp_mov(float v) {
    int i = __builtin_bit_cast(int, v);
    i = __builtin_amdgcn_mov_dpp(i, CTRL, 0xF, 0xF, true);
    return __builtin_bit_cast(float, i);
}

#define DPP_QUAD_BCAST0 0x00   // quad_perm [0,0,0,0] -> i gate
#define DPP_QUAD_BCAST1 0x55   // quad_perm [1,1,1,1] -> f gate
#define DPP_QUAD_BCAST2 0xAA   // quad_perm [2,2,2,2] -> g gate
#define DPP_QUAD_BCAST3 0xFF   // quad_perm [3,3,3,3] -> o gate
#define DPP_ROR8        0x128  // l^8  -> u^2 (on quad-uniform data)
#define DPP_MIRROR      0x140  // l^15 -> u^3 (on quad-uniform data)
#define DPP_HALF_MIRROR 0x141  // l^7  -> u^1 (on quad-uniform data)

__global__ __launch_bounds__(768) void lstm_3stage_kernel(
    const float* __restrict__ x,
    const float* __restrict__ W_ih0, const float* __restrict__ W_hh0,
    const float* __restrict__ b_ih0, const float* __restrict__ b_hh0,
    const float* __restrict__ W_ih1, const float* __restrict__ W_hh1,
    const float* __restrict__ b_ih1, const float* __restrict__ b_hh1,
    const float* __restrict__ W1, const float* __restrict__ b1,
    const float* __restrict__ W2, const float* __restrict__ b2,
    float* __restrict__ out)
{
    // Rings: plain h[4] per chain. [triple][slot][step][chain] = 8 KB each.
    __shared__ float4 ring0[4][2][CHUNK][4];
    __shared__ float4 ring1[4][2][CHUNK][4];

    const int tid  = threadIdx.x;
    const int wave = tid >> 6;
    const int tr   = wave / 3;          // triple (chain-quad) 0..3
    const int stg  = wave % 3;          // 0 = L0, 1 = L1, 2 = head
    const int lane = tid & 63;
    const int idx  = lane & 15;         // lane within 16-lane chain group
    const int rho  = lane & 3;          // role: 0=i,1=f,2=g,3=o
    const int u    = (lane >> 2) & 3;   // hidden unit
    const int r    = rho * 4 + u;       // gate row in 16-row weight matrices
    const int ch   = lane >> 4;         // chain within triple
    const int batch = blockIdx.x * 16 + tr * 4 + ch;

    // Per-lane activation constants: role g (rho==2) uses tanh = 2*sigma(2x)-1.
    const float am = (rho == 2) ? -2.88539008f : -1.44269504f;
    const float aa = (rho == 2) ? 2.0f : 1.0f;
    const float ab = (rho == 2) ? -1.0f : 0.0f;

    // ---- stage 0 constants ----
    const float wx0 = W_ih0[r * 3 + 0];
    const float wx1 = W_ih0[r * 3 + 1];
    const float wx2 = W_ih0[r * 3 + 2];
    const float bias0 = b_ih0[r] + b_hh0[r];
    float wh0[4];
#pragma unroll
    for (int k = 0; k < 4; ++k) wh0[k] = W_hh0[r * 4 + (u ^ k)];   // xor order

    // ---- stage 1 constants ----
    const float bias1 = b_ih1[r] + b_hh1[r];
    float wi1[4], wh1[4];
#pragma unroll
    for (int k = 0; k < 4; ++k) {
        wi1[k] = W_ih1[r * 4 + k];          // PLAIN order (ring h is plain)
        wh1[k] = W_hh1[r * 4 + (u ^ k)];    // xor order (register quad)
    }

    // ---- stage 2 constants ----
    float w1p[4];
#pragma unroll
    for (int k = 0; k < 4; ++k) w1p[k] = W1[u * 4 + k];   // PLAIN order
    const float b1u = b1[u];
    const float w2u = W2[u];
    const float b2v = b2[0];

    // ---- per-stage state ----
    float h0 = 0.f, c0 = 0.f, h0b = 0.f, h0c = 0.f, h0d = 0.f;   // stage 0
    float h1 = 0.f, c1 = 0.f, h1b = 0.f, h1c = 0.f, h1d = 0.f;   // stage 1
    float ysave = 0.f;                                            // stage 2
    float* op = out + (size_t)batch * T_STEPS;

    const float* xp = x + (size_t)batch * T_STEPS * 3;
    float ax0 = 0.f, ax1 = 0.f, ax2 = 0.f, bx0 = 0.f, bx1 = 0.f, bx2 = 0.f;
    if (stg == 0) {   // prime 2-deep x prefetch
        ax0 = xp[0]; ax1 = xp[1]; ax2 = xp[2];
        bx0 = xp[3]; bx1 = xp[4]; bx2 = xp[5];
        xp += 6;
    }

    for (int c = 0; c < NCHUNK + 2; ++c) {
        if (stg == 0) {
            if (c < NCHUNK) {
                // ============ stage 0: layer 0, chunk c ============
                const int s = c & 1;
#pragma unroll
                for (int tt = 0; tt < CHUNK; ++tt) {
                    const int t = c * CHUNK + tt;
                    const float x0 = ax0, x1 = ax1, x2 = ax2;
                    ax0 = bx0; ax1 = bx1; ax2 = bx2;
                    const float* xl = (t < T_STEPS - 2) ? xp : (xp - 6);
                    bx0 = xl[0]; bx1 = xl[1]; bx2 = xl[2];
                    xp += 3;

                    float pre0 = bias0 + wx0 * x0 + wx1 * x1 + wx2 * x2
                               + wh0[0] * h0 + wh0[1] * h0b + wh0[2] * h0c + wh0[3] * h0d;
                    float a0 = aa * fast_rcp(1.0f + fast_exp2(am * pre0)) + ab;
                    float gi = dpp_mov<DPP_QUAD_BCAST0>(a0);
                    float gf = dpp_mov<DPP_QUAD_BCAST1>(a0);
                    float gg = dpp_mov<DPP_QUAD_BCAST2>(a0);
                    float go = dpp_mov<DPP_QUAD_BCAST3>(a0);
                    c0 = gf * c0 + gi * gg;
                    h0 = go * fast_tanh(c0);
                    h0b = dpp_mov<DPP_HALF_MIRROR>(h0);
                    h0c = dpp_mov<DPP_ROR8>(h0);
                    h0d = dpp_mov<DPP_MIRROR>(h0);

                    if (rho == 0) ((float*)&ring0[tr][s][tt][ch])[u] = h0;  // plain h0[u]
                }
            }
        } else if (stg == 1) {
            if (c >= 1 && c <= NCHUNK) {
                // ============ stage 1: layer 1, chunk c-1 ============
                const int cc = c - 1;
                const int s = cc & 1;
                float4 hcur = ring0[tr][s][0][ch];
#pragma unroll
                for (int tt = 0; tt < CHUNK; ++tt) {
                    float4 hnxt = ring0[tr][s][(tt < CHUNK - 1) ? tt + 1 : tt][ch];

                    float pre1 = bias1
                               + wi1[0] * hcur.x + wi1[1] * hcur.y
                               + wi1[2] * hcur.z + wi1[3] * hcur.w
                               + wh1[0] * h1 + wh1[1] * h1b + wh1[2] * h1c + wh1[3] * h1d;
                    float a1 = aa * fast_rcp(1.0f + fast_exp2(am * pre1)) + ab;
                    float gi1 = dpp_mov<DPP_QUAD_BCAST0>(a1);
                    float gf1 = dpp_mov<DPP_QUAD_BCAST1>(a1);
                    float gg1 = dpp_mov<DPP_QUAD_BCAST2>(a1);
                    float go1 = dpp_mov<DPP_QUAD_BCAST3>(a1);
                    c1 = gf1 * c1 + gi1 * gg1;
                    h1 = go1 * fast_tanh(c1);
                    h1b = dpp_mov<DPP_HALF_MIRROR>(h1);
                    h1c = dpp_mov<DPP_ROR8>(h1);
                    h1d = dpp_mov<DPP_MIRROR>(h1);

                    if (rho == 0) ((float*)&ring1[tr][s][tt][ch])[u] = h1;  // plain h1[u]
                    hcur = hnxt;
                }
            }
        } else {
            if (c >= 2) {
                // ============ stage 2: head + store, chunk c-2 ============
                const int cc = c - 2;
                const int s = cc & 1;
                float4 hcur = ring1[tr][s][0][ch];
#pragma unroll
                for (int tt = 0; tt < CHUNK; ++tt) {
                    float4 hnxt = ring1[tr][s][(tt < CHUNK - 1) ? tt + 1 : tt][ch];

                    float zp = b1u + w1p[0] * hcur.x + w1p[1] * hcur.y
                                   + w1p[2] * hcur.z + w1p[3] * hcur.w;
                    float z  = fast_tanh(zp);
                    float yv = w2u * z;                              // quad-uniform
                    float t1 = yv + dpp_mov<DPP_ROR8>(yv);           // + unit u^2
                    float y  = t1 + dpp_mov<DPP_MIRROR>(t1) + b2v;   // + units u^1,u^3

                    ysave = (tt == idx) ? y : ysave;
                    hcur = hnxt;
                }
                op[cc * CHUNK + idx] = ysave;   // 16 consecutive floats per chain
            }
        }
        __syncthreads();
    }
}

extern "C" void kernel_launch(void* const* d_in, const int* in_sizes, int n_in,
                              void* d_out, int out_size, void* d_ws, size_t ws_size,
                              hipStream_t stream) {
    const float* x     = (const float*)d_in[0];
    const float* W_ih0 = (const float*)d_in[1];
    const float* W_hh0 = (const float*)d_in[2];
    const float* b_ih0 = (const float*)d_in[3];
    const float* b_hh0 = (const float*)d_in[4];
    const float* W_ih1 = (const float*)d_in[5];
    const float* W_hh1 = (const float*)d_in[6];
    const float* b_ih1 = (const float*)d_in[7];
    const float* b_hh1 = (const float*)d_in[8];
    const float* W1    = (const float*)d_in[9];
    const float* b1    = (const float*)d_in[10];
    const float* W2    = (const float*)d_in[11];
    const float* b2    = (const float*)d_in[12];
    float* out = (float*)d_out;

    dim3 grid(BATCH / 16);   // 256 blocks = 1 per CU, 16 chains each
    dim3 block(768);         // 12 waves = 4 triples x 3 stages; 3 waves/SIMD
    lstm_3stage_kernel<<<grid, block, 0, stream>>>(
        x, W_ih0, W_hh0, b_ih0, b_hh0, W_ih1, W_hh1, b_ih1, b_hh1,
        W1, b1, W2, b2, out);
}